// Round 2
// baseline (204.955 us; speedup 1.0000x reference)
//
#include <hip/hip_runtime.h>

#define HN 32
#define MM 16
#define DD 128
#define NN 4096
#define PP 8192
#define TP 64

// ---------------- Kernel 1: QKV projection (atomic accumulate) ----------------
// grid = 768 : mat(3) x coltile(8 x 512) x rowchunk(32 x 128); float2 W loads
__global__ __launch_bounds__(256) void qkv_kernel(
    const float* __restrict__ X, const float* __restrict__ Wq,
    const float* __restrict__ Wk, const float* __restrict__ Wv,
    float* __restrict__ qkv)
{
    __shared__ float Xs[MM][128];
    const int bx  = blockIdx.x;
    const int mat = bx >> 8;
    const int r   = bx & 255;
    const int ct  = r >> 5;           // 0..7
    const int rc  = r & 31;           // 0..31
    const int col0 = ct << 9;
    const int i0   = rc << 7;
    const float* W = (mat == 0) ? Wq : (mat == 1) ? Wk : Wv;
    const int t = threadIdx.x;

    for (int f = t; f < MM*128; f += 256)
        Xs[f >> 7][f & 127] = X[(f >> 7)*NN + i0 + (f & 127)];
    __syncthreads();

    const int c0 = col0 + 2*t;        // 2 consecutive cols per thread
    float a0[MM], a1[MM];
#pragma unroll
    for (int m = 0; m < MM; ++m) { a0[m] = 0.f; a1[m] = 0.f; }

    for (int i4 = 0; i4 < 128; i4 += 4) {
        const float* Wr = W + (size_t)(i0 + i4) * NN + c0;
        float2 w0 = *reinterpret_cast<const float2*>(Wr);
        float2 w1 = *reinterpret_cast<const float2*>(Wr + NN);
        float2 w2 = *reinterpret_cast<const float2*>(Wr + 2*NN);
        float2 w3 = *reinterpret_cast<const float2*>(Wr + 3*NN);
#pragma unroll
        for (int m = 0; m < MM; ++m) {
            float4 x = *reinterpret_cast<const float4*>(&Xs[m][i4]);
            a0[m] += x.x*w0.x + x.y*w1.x + x.z*w2.x + x.w*w3.x;
            a1[m] += x.x*w0.y + x.y*w1.y + x.z*w2.y + x.w*w3.y;
        }
    }
    const int h0 = c0 >> 7, d0 = c0 & 127;
    float* base = qkv + (size_t)mat * HN*MM*DD + (size_t)h0*MM*DD + d0;
#pragma unroll
    for (int m = 0; m < MM; ++m) {
        atomicAdd(base + m*DD,     a0[m]);
        atomicAdd(base + m*DD + 1, a1[m]);
    }
}

// ---------------- Kernel 2: flash-decode partials, wave-owns-4-rows ----------------
// grid = (nch, HN), block 256 (4 waves; wave w owns m rows 4w..4w+3)
__global__ __launch_bounds__(256, 4) void attn_partial2(
    const float* __restrict__ cacheK, const float* __restrict__ cacheV,
    const float* __restrict__ qkv, float* __restrict__ pmu,
    float* __restrict__ ps, float* __restrict__ pacc,
    int nch, int chunklen)
{
    __shared__ float KV[TP][DD + 4];   // 64 x 132 floats = 33.8 KB
    __shared__ float Wl[MM][68];       // weights [m][p], 4.35 KB

    const int chunk = blockIdx.x;
    const int h     = blockIdx.y;
    const int t     = threadIdx.x;
    const int lane  = t & 63;
    const int w     = __builtin_amdgcn_readfirstlane((int)(threadIdx.x >> 6));
    const int psi   = lane >> 4;       // p-quarter for PV
    const int g     = lane & 15;       // d-slice (8 floats) for PV

    const float* k_ws = qkv + HN*MM*DD;
    const float* v_ws = qkv + 2*HN*MM*DD;
    const float* qb   = qkv + (size_t)(h*MM + 4*w)*DD;   // wave's 4 Q rows (uniform addr)

    const int cnt   = (chunk < nch - 1) ? chunklen : MM;
    const int ntile = (cnt + TP - 1) / TP;

    float mu0 = -3.0e38f, mu1 = -3.0e38f, mu2 = -3.0e38f, mu3 = -3.0e38f;
    float ss0 = 0.f, ss1 = 0.f, ss2 = 0.f, ss3 = 0.f;
    float acc[4][8];
#pragma unroll
    for (int q = 0; q < 4; ++q)
#pragma unroll
        for (int k = 0; k < 8; ++k) acc[q][k] = 0.f;

    const int srow = t >> 5, sc4 = t & 31;   // staging role

    for (int tt = 0; tt < ntile; ++tt) {
        const int t0 = tt * TP;
        const int valid = min(TP, cnt - t0);

        __syncthreads();           // previous PV readers done with KV
        // ---- stage K tile ----
#pragma unroll
        for (int rr = 0; rr < 8; ++rr) {
            const int r2 = srow + rr*8;
            float4 v = make_float4(0.f, 0.f, 0.f, 0.f);
            if (r2 < valid) {
                const float* kp = (chunk < nch - 1)
                    ? cacheK + ((size_t)h*PP + (size_t)chunk*chunklen + t0 + r2)*DD
                    : k_ws + (size_t)(h*MM + t0 + r2)*DD;
                v = reinterpret_cast<const float4*>(kp)[sc4];
            }
            *reinterpret_cast<float4*>(&KV[r2][sc4*4]) = v;
        }
        __syncthreads();

        // ---- scores: lane p = lane, 4 m-rows of this wave ----
        float s0 = 0.f, s1 = 0.f, s2 = 0.f, s3 = 0.f;
#pragma unroll 8
        for (int dq = 0; dq < 32; ++dq) {
            float4 k = *reinterpret_cast<const float4*>(&KV[lane][dq*4]);
            const float* qp = qb + dq*4;
            float4 q0 = *reinterpret_cast<const float4*>(qp);
            float4 q1 = *reinterpret_cast<const float4*>(qp + DD);
            float4 q2 = *reinterpret_cast<const float4*>(qp + 2*DD);
            float4 q3 = *reinterpret_cast<const float4*>(qp + 3*DD);
            s0 += k.x*q0.x + k.y*q0.y + k.z*q0.z + k.w*q0.w;
            s1 += k.x*q1.x + k.y*q1.y + k.z*q1.z + k.w*q1.w;
            s2 += k.x*q2.x + k.y*q2.y + k.z*q2.z + k.w*q2.w;
            s3 += k.x*q3.x + k.y*q3.y + k.z*q3.z + k.w*q3.w;
        }
        if (lane >= valid) { s0 = s1 = s2 = s3 = -3.0e38f; }
        __syncthreads();           // K consumed; KV free for V

        // ---- stage V tile (issue loads first; softmax hides latency) ----
#pragma unroll
        for (int rr = 0; rr < 8; ++rr) {
            const int r2 = srow + rr*8;
            float4 v = make_float4(0.f, 0.f, 0.f, 0.f);
            if (r2 < valid) {
                const float* vp = (chunk < nch - 1)
                    ? cacheV + ((size_t)h*PP + (size_t)chunk*chunklen + t0 + r2)*DD
                    : v_ws + (size_t)(h*MM + t0 + r2)*DD;
                v = reinterpret_cast<const float4*>(vp)[sc4];
            }
            *reinterpret_cast<float4*>(&KV[r2][sc4*4]) = v;
        }

        // ---- softmax: registers + wave all-reduce only ----
        float m0 = s0, m1 = s1, m2 = s2, m3 = s3;
#pragma unroll
        for (int off = 1; off < 64; off <<= 1) {
            m0 = fmaxf(m0, __shfl_xor(m0, off));
            m1 = fmaxf(m1, __shfl_xor(m1, off));
            m2 = fmaxf(m2, __shfl_xor(m2, off));
            m3 = fmaxf(m3, __shfl_xor(m3, off));
        }
        const float n0 = fmaxf(mu0, m0), n1 = fmaxf(mu1, m1);
        const float n2 = fmaxf(mu2, m2), n3 = fmaxf(mu3, m3);
        const float r0 = __expf(mu0 - n0), r1 = __expf(mu1 - n1);
        const float r2_ = __expf(mu2 - n2), r3 = __expf(mu3 - n3);
        float w0 = (lane < valid) ? __expf(s0 - n0) : 0.f;
        float w1 = (lane < valid) ? __expf(s1 - n1) : 0.f;
        float w2 = (lane < valid) ? __expf(s2 - n2) : 0.f;
        float w3 = (lane < valid) ? __expf(s3 - n3) : 0.f;
        float t0s = w0, t1s = w1, t2s = w2, t3s = w3;
#pragma unroll
        for (int off = 1; off < 64; off <<= 1) {
            t0s += __shfl_xor(t0s, off);
            t1s += __shfl_xor(t1s, off);
            t2s += __shfl_xor(t2s, off);
            t3s += __shfl_xor(t3s, off);
        }
        ss0 = ss0*r0 + t0s; ss1 = ss1*r1 + t1s;
        ss2 = ss2*r2_ + t2s; ss3 = ss3*r3 + t3s;
        mu0 = n0; mu1 = n1; mu2 = n2; mu3 = n3;
        Wl[4*w + 0][lane] = w0;
        Wl[4*w + 1][lane] = w1;
        Wl[4*w + 2][lane] = w2;
        Wl[4*w + 3][lane] = w3;
        __syncthreads();           // V staged + weights written

        // ---- PV accumulate: lane (psi, g) -> p in {psi,psi+4,...}, d in [8g,8g+8) ----
#pragma unroll
        for (int k = 0; k < 8; ++k) {
            acc[0][k] *= r0; acc[1][k] *= r1; acc[2][k] *= r2_; acc[3][k] *= r3;
        }
#pragma unroll 4
        for (int p = psi; p < TP; p += 4) {
            float wq[4];
            wq[0] = Wl[4*w + 0][p];
            wq[1] = Wl[4*w + 1][p];
            wq[2] = Wl[4*w + 2][p];
            wq[3] = Wl[4*w + 3][p];
            float4 v0 = *reinterpret_cast<const float4*>(&KV[p][g*8]);
            float4 v1 = *reinterpret_cast<const float4*>(&KV[p][g*8 + 4]);
#pragma unroll
            for (int q = 0; q < 4; ++q) {
                acc[q][0] += wq[q]*v0.x; acc[q][1] += wq[q]*v0.y;
                acc[q][2] += wq[q]*v0.z; acc[q][3] += wq[q]*v0.w;
                acc[q][4] += wq[q]*v1.x; acc[q][5] += wq[q]*v1.y;
                acc[q][6] += wq[q]*v1.z; acc[q][7] += wq[q]*v1.w;
            }
        }
    }

    // ---- epilogue: reduce psi-partials via shuffles, write partials ----
#pragma unroll
    for (int q = 0; q < 4; ++q)
#pragma unroll
        for (int k = 0; k < 8; ++k) {
            float v = acc[q][k];
            v += __shfl_xor(v, 16);
            v += __shfl_xor(v, 32);
            acc[q][k] = v;
        }
    if (psi == 0) {
        float* pa = pacc + ((size_t)(h*nch + chunk)*MM + 4*w)*DD;
#pragma unroll
        for (int q = 0; q < 4; ++q) {
            *reinterpret_cast<float4*>(pa + q*DD + g*8) =
                make_float4(acc[q][0], acc[q][1], acc[q][2], acc[q][3]);
            *reinterpret_cast<float4*>(pa + q*DD + g*8 + 4) =
                make_float4(acc[q][4], acc[q][5], acc[q][6], acc[q][7]);
        }
    }
    if (lane == 0) {
        const int o = (h*nch + chunk)*MM + 4*w;
        pmu[o + 0] = mu0; pmu[o + 1] = mu1; pmu[o + 2] = mu2; pmu[o + 3] = mu3;
        ps [o + 0] = ss0; ps [o + 1] = ss1; ps [o + 2] = ss2; ps [o + 3] = ss3;
    }
}

// ---------------- Kernel 3: combine partials (runtime nch) ----------------
__global__ __launch_bounds__(128) void combine_kernel(
    const float* __restrict__ pmu, const float* __restrict__ ps,
    const float* __restrict__ pacc, float* __restrict__ out, int nch)
{
    const int b = blockIdx.x;          // h*16 + m
    const int h = b >> 4, m = b & 15;
    const int d = threadIdx.x;
    float gm = -3.0e38f;
    for (int c = 0; c < nch; ++c)
        gm = fmaxf(gm, pmu[(h*nch + c)*MM + m]);
    float stot = 0.f, a = 0.f;
    for (int c = 0; c < nch; ++c) {
        const float f = __expf(pmu[(h*nch + c)*MM + m] - gm);
        stot += ps[(h*nch + c)*MM + m] * f;
        a += pacc[((size_t)(h*nch + c)*MM + m)*DD + d] * f;
    }
    out[m*NN + h*DD + d] = a / stot;
}

static size_t ws_need_floats(int nch) {
    return (size_t)3*HN*MM*DD + 2*(size_t)HN*nch*MM + (size_t)HN*nch*MM*DD;
}

extern "C" void kernel_launch(void* const* d_in, const int* in_sizes, int n_in,
                              void* d_out, int out_size, void* d_ws, size_t ws_size,
                              hipStream_t stream) {
    const float* X  = (const float*)d_in[0];
    const float* Wq = (const float*)d_in[1];
    const float* Wk = (const float*)d_in[2];
    const float* Wv = (const float*)d_in[3];
    const float* cK = (const float*)d_in[4];
    const float* cV = (const float*)d_in[5];
    float* out = (float*)d_out;

    int nch = 65;                                   // 64 cache chunks of 128 + 1 new
    if (ws_size < ws_need_floats(65)*sizeof(float)) nch = 33;
    if (ws_size < ws_need_floats(33)*sizeof(float)) nch = 17;
    const int chunklen = PP / (nch - 1);

    float* ws     = (float*)d_ws;
    float* qkv    = ws;
    float* pmu_p  = ws + 3*HN*MM*DD;
    float* ps_p   = pmu_p + (size_t)HN*nch*MM;
    float* pacc_p = ps_p + (size_t)HN*nch*MM;

    hipMemsetAsync(qkv, 0, (size_t)3*HN*MM*DD*sizeof(float), stream);
    qkv_kernel<<<768, 256, 0, stream>>>(X, Wq, Wk, Wv, qkv);
    attn_partial2<<<dim3(nch, HN), 256, 0, stream>>>(cK, cV, qkv, pmu_p, ps_p, pacc_p,
                                                     nch, chunklen);
    combine_kernel<<<HN*MM, 128, 0, stream>>>(pmu_p, ps_p, pacc_p, out, nch);
}

// Round 3
// 174.679 us; speedup vs baseline: 1.1733x; 1.1733x over previous
//
#include <hip/hip_runtime.h>

#define HN 32
#define MM 16
#define DD 128
#define NN 4096
#define PP 8192
#define TP 64
#define NCH 16
#define CHUNKLEN (PP / NCH)      // 512 cache rows per chunk

// ---------------- Kernel 1: QKV projection (atomic accumulate) ----------------
// grid = 768 : mat(3) x coltile(8 x 512) x rowchunk(32 x 128); deep unroll for MLP
__global__ __launch_bounds__(256) void qkv_kernel(
    const float* __restrict__ X, const float* __restrict__ Wq,
    const float* __restrict__ Wk, const float* __restrict__ Wv,
    float* __restrict__ qkv)
{
    __shared__ float Xs[MM][128];
    const int bx  = blockIdx.x;
    const int mat = bx >> 8;
    const int r   = bx & 255;
    const int ct  = r >> 5;           // 0..7
    const int rc  = r & 31;           // 0..31
    const int col0 = ct << 9;
    const int i0   = rc << 7;
    const float* W = (mat == 0) ? Wq : (mat == 1) ? Wk : Wv;
    const int t = threadIdx.x;

    for (int f = t; f < MM*128; f += 256)
        Xs[f >> 7][f & 127] = X[(f >> 7)*NN + i0 + (f & 127)];
    __syncthreads();

    const int c0 = col0 + t, c1 = col0 + 256 + t;
    float a0[MM], a1[MM];
#pragma unroll
    for (int m = 0; m < MM; ++m) { a0[m] = 0.f; a1[m] = 0.f; }

    for (int i8 = 0; i8 < 128; i8 += 8) {
        const float* Wr = W + (size_t)(i0 + i8) * NN;
        float w0[8], w1[8];
#pragma unroll
        for (int rr = 0; rr < 8; ++rr) {        // 16 loads in flight
            w0[rr] = Wr[rr*NN + c0];
            w1[rr] = Wr[rr*NN + c1];
        }
#pragma unroll
        for (int m = 0; m < MM; ++m) {
            float4 xa = *reinterpret_cast<const float4*>(&Xs[m][i8]);
            float4 xb = *reinterpret_cast<const float4*>(&Xs[m][i8 + 4]);
            a0[m] += xa.x*w0[0] + xa.y*w0[1] + xa.z*w0[2] + xa.w*w0[3]
                   + xb.x*w0[4] + xb.y*w0[5] + xb.z*w0[6] + xb.w*w0[7];
            a1[m] += xa.x*w1[0] + xa.y*w1[1] + xa.z*w1[2] + xa.w*w1[3]
                   + xb.x*w1[4] + xb.y*w1[5] + xb.z*w1[6] + xb.w*w1[7];
        }
    }
    float* base = qkv + (size_t)mat * HN*MM*DD;
    const int h0 = c0 >> 7, d0 = c0 & 127;
    const int h1 = c1 >> 7, d1 = c1 & 127;
#pragma unroll
    for (int m = 0; m < MM; ++m) {
        atomicAdd(&base[(h0*MM + m)*DD + d0], a0[m]);
        atomicAdd(&base[(h1*MM + m)*DD + d1], a1[m]);
    }
}

// ---------------- Kernel 2: flash-decode partials, dbuf + async-stage ----------------
// grid = (NCH=16, HN=32) = 512 blocks = exactly 2/CU. 4 waves; wave owns m rows 4w..4w+3.
__global__ __launch_bounds__(256, 2) void attn_partial3(
    const float* __restrict__ cacheK, const float* __restrict__ cacheV,
    const float* __restrict__ qkv, float* __restrict__ pmu,
    float* __restrict__ ps, float* __restrict__ pacc)
{
    __shared__ float KA[TP][DD + 4];   // K tile, 33.8 KB
    __shared__ float KB[TP][DD + 4];   // V tile, 33.8 KB
    __shared__ float Wl[TP][20];       // weights [p][m], b128 rows, 5 KB

    const int chunk = blockIdx.x;
    const int h     = blockIdx.y;
    const int t     = threadIdx.x;
    const int lane  = t & 63;
    const int wv    = t >> 6;          // wave id (uniform per wave)
    const int srow0 = t >> 5;          // staging row base 0..7
    const int sg    = t & 31;          // staging granule (16B)
    const int psi   = lane >> 4;       // p-quarter for PV
    const int g     = lane & 15;       // d-slice (8 floats) for PV

    const float* k_ws = qkv + HN*MM*DD;
    const float* v_ws = qkv + 2*HN*MM*DD;
    const float* Kbase = cacheK + ((size_t)h*PP + (size_t)chunk*CHUNKLEN)*DD;
    const float* Vbase = cacheV + ((size_t)h*PP + (size_t)chunk*CHUNKLEN)*DD;
    const float* qb    = qkv + ((size_t)h*MM + 4*wv)*DD;   // wave-uniform

    const int nfull = CHUNKLEN / TP;                       // 8
    const int ntile = nfull + (chunk == NCH - 1 ? 1 : 0);  // +1 partial (16 new rows)

    float mu0 = -3.0e38f, mu1 = -3.0e38f, mu2 = -3.0e38f, mu3 = -3.0e38f;
    float ss0 = 0.f, ss1 = 0.f, ss2 = 0.f, ss3 = 0.f;
    float acc[4][8];
#pragma unroll
    for (int q = 0; q < 4; ++q)
#pragma unroll
        for (int k = 0; k < 8; ++k) acc[q][k] = 0.f;

    float4 stK[8], stV[8];

    auto issueK = [&](int tt2) {
        if (tt2 < nfull) {
            const float* B = Kbase + (size_t)(tt2*TP)*DD;
#pragma unroll
            for (int rr = 0; rr < 8; ++rr)
                stK[rr] = *reinterpret_cast<const float4*>(B + (size_t)(srow0 + 8*rr)*DD + sg*4);
        } else {
#pragma unroll
            for (int rr = 0; rr < 8; ++rr) {
                const int row = srow0 + 8*rr;
                stK[rr] = (row < MM)
                    ? *reinterpret_cast<const float4*>(k_ws + ((size_t)h*MM + row)*DD + sg*4)
                    : make_float4(0.f, 0.f, 0.f, 0.f);
            }
        }
    };
    auto issueV = [&](int tt2) {
        if (tt2 < nfull) {
            const float* B = Vbase + (size_t)(tt2*TP)*DD;
#pragma unroll
            for (int rr = 0; rr < 8; ++rr)
                stV[rr] = *reinterpret_cast<const float4*>(B + (size_t)(srow0 + 8*rr)*DD + sg*4);
        } else {
#pragma unroll
            for (int rr = 0; rr < 8; ++rr) {
                const int row = srow0 + 8*rr;
                stV[rr] = (row < MM)
                    ? *reinterpret_cast<const float4*>(v_ws + ((size_t)h*MM + row)*DD + sg*4)
                    : make_float4(0.f, 0.f, 0.f, 0.f);
            }
        }
    };

    issueK(0);   // prologue prefetch

    for (int tt = 0; tt < ntile; ++tt) {
        const int valid = (tt < nfull) ? TP : MM;

        // write K tile (KA free: scores(tt-1) readers finished before B2(tt-1))
#pragma unroll
        for (int rr = 0; rr < 8; ++rr)
            *reinterpret_cast<float4*>(&KA[srow0 + 8*rr][sg*4]) = stK[rr];

        issueV(tt);                       // V loads in flight across B1 + scores

        __syncthreads();                  // B1: K visible; PV(tt-1) done (KB free)

        // ---- scores: lane p = lane, 4 m-rows; Q via wave-uniform global (L1-hot) ----
        float s0 = 0.f, s1 = 0.f, s2 = 0.f, s3 = 0.f;
#pragma unroll 4
        for (int dq = 0; dq < 32; ++dq) {
            float4 k = *reinterpret_cast<const float4*>(&KA[lane][dq*4]);
            const float* qp = qb + dq*4;
            float4 q0 = *reinterpret_cast<const float4*>(qp);
            float4 q1 = *reinterpret_cast<const float4*>(qp + DD);
            float4 q2 = *reinterpret_cast<const float4*>(qp + 2*DD);
            float4 q3 = *reinterpret_cast<const float4*>(qp + 3*DD);
            s0 += k.x*q0.x + k.y*q0.y + k.z*q0.z + k.w*q0.w;
            s1 += k.x*q1.x + k.y*q1.y + k.z*q1.z + k.w*q1.w;
            s2 += k.x*q2.x + k.y*q2.y + k.z*q2.z + k.w*q2.w;
            s3 += k.x*q3.x + k.y*q3.y + k.z*q3.z + k.w*q3.w;
        }
        if (lane >= valid) { s0 = s1 = s2 = s3 = -3.0e38f; }

        // write V tile (KB free since B1; other waves only read KA here)
#pragma unroll
        for (int rr = 0; rr < 8; ++rr)
            *reinterpret_cast<float4*>(&KB[srow0 + 8*rr][sg*4]) = stV[rr];

        if (tt + 1 < ntile) issueK(tt + 1);   // in flight across softmax+PV+B2

        // ---- softmax: registers + wave all-reduce ----
        float m0 = s0, m1 = s1, m2 = s2, m3 = s3;
#pragma unroll
        for (int off = 1; off < 64; off <<= 1) {
            m0 = fmaxf(m0, __shfl_xor(m0, off));
            m1 = fmaxf(m1, __shfl_xor(m1, off));
            m2 = fmaxf(m2, __shfl_xor(m2, off));
            m3 = fmaxf(m3, __shfl_xor(m3, off));
        }
        const float n0 = fmaxf(mu0, m0), n1 = fmaxf(mu1, m1);
        const float n2 = fmaxf(mu2, m2), n3 = fmaxf(mu3, m3);
        const float r0 = __expf(mu0 - n0), r1 = __expf(mu1 - n1);
        const float r2_ = __expf(mu2 - n2), r3 = __expf(mu3 - n3);
        float w0 = (lane < valid) ? __expf(s0 - n0) : 0.f;
        float w1 = (lane < valid) ? __expf(s1 - n1) : 0.f;
        float w2 = (lane < valid) ? __expf(s2 - n2) : 0.f;
        float w3 = (lane < valid) ? __expf(s3 - n3) : 0.f;
        float t0s = w0, t1s = w1, t2s = w2, t3s = w3;
#pragma unroll
        for (int off = 1; off < 64; off <<= 1) {
            t0s += __shfl_xor(t0s, off);
            t1s += __shfl_xor(t1s, off);
            t2s += __shfl_xor(t2s, off);
            t3s += __shfl_xor(t3s, off);
        }
        ss0 = ss0*r0 + t0s; ss1 = ss1*r1 + t1s;
        ss2 = ss2*r2_ + t2s; ss3 = ss3*r3 + t3s;
        mu0 = n0; mu1 = n1; mu2 = n2; mu3 = n3;
        // weights: lane p writes its wave's 4 m-cols in one b128 (same-wave consumer)
        *reinterpret_cast<float4*>(&Wl[lane][4*wv]) = make_float4(w0, w1, w2, w3);

        __syncthreads();                  // B2: V visible to all waves

        // ---- PV accumulate ----
#pragma unroll
        for (int k = 0; k < 8; ++k) {
            acc[0][k] *= r0; acc[1][k] *= r1; acc[2][k] *= r2_; acc[3][k] *= r3;
        }
#pragma unroll 4
        for (int i = 0; i < 16; ++i) {
            const int p = psi + 4*i;
            float4 wq = *reinterpret_cast<const float4*>(&Wl[p][4*wv]);
            float4 v0 = *reinterpret_cast<const float4*>(&KB[p][g*8]);
            float4 v1 = *reinterpret_cast<const float4*>(&KB[p][g*8 + 4]);
            acc[0][0] += wq.x*v0.x; acc[0][1] += wq.x*v0.y; acc[0][2] += wq.x*v0.z; acc[0][3] += wq.x*v0.w;
            acc[0][4] += wq.x*v1.x; acc[0][5] += wq.x*v1.y; acc[0][6] += wq.x*v1.z; acc[0][7] += wq.x*v1.w;
            acc[1][0] += wq.y*v0.x; acc[1][1] += wq.y*v0.y; acc[1][2] += wq.y*v0.z; acc[1][3] += wq.y*v0.w;
            acc[1][4] += wq.y*v1.x; acc[1][5] += wq.y*v1.y; acc[1][6] += wq.y*v1.z; acc[1][7] += wq.y*v1.w;
            acc[2][0] += wq.z*v0.x; acc[2][1] += wq.z*v0.y; acc[2][2] += wq.z*v0.z; acc[2][3] += wq.z*v0.w;
            acc[2][4] += wq.z*v1.x; acc[2][5] += wq.z*v1.y; acc[2][6] += wq.z*v1.z; acc[2][7] += wq.z*v1.w;
            acc[3][0] += wq.w*v0.x; acc[3][1] += wq.w*v0.y; acc[3][2] += wq.w*v0.z; acc[3][3] += wq.w*v0.w;
            acc[3][4] += wq.w*v1.x; acc[3][5] += wq.w*v1.y; acc[3][6] += wq.w*v1.z; acc[3][7] += wq.w*v1.w;
        }
    }

    // ---- epilogue: reduce psi-partials via shuffles, write partials ----
#pragma unroll
    for (int q = 0; q < 4; ++q)
#pragma unroll
        for (int k = 0; k < 8; ++k) {
            float v = acc[q][k];
            v += __shfl_xor(v, 16);
            v += __shfl_xor(v, 32);
            acc[q][k] = v;
        }
    if (psi == 0) {
        float* pa = pacc + ((size_t)(h*NCH + chunk)*MM + 4*wv)*DD;
#pragma unroll
        for (int q = 0; q < 4; ++q) {
            *reinterpret_cast<float4*>(pa + q*DD + g*8) =
                make_float4(acc[q][0], acc[q][1], acc[q][2], acc[q][3]);
            *reinterpret_cast<float4*>(pa + q*DD + g*8 + 4) =
                make_float4(acc[q][4], acc[q][5], acc[q][6], acc[q][7]);
        }
    }
    if (lane == 0) {
        const int o = (h*NCH + chunk)*MM + 4*wv;
        pmu[o + 0] = mu0; pmu[o + 1] = mu1; pmu[o + 2] = mu2; pmu[o + 3] = mu3;
        ps [o + 0] = ss0; ps [o + 1] = ss1; ps [o + 2] = ss2; ps [o + 3] = ss3;
    }
}

// ---------------- Kernel 3: combine partials ----------------
__global__ __launch_bounds__(128) void combine_kernel(
    const float* __restrict__ pmu, const float* __restrict__ ps,
    const float* __restrict__ pacc, float* __restrict__ out)
{
    const int b = blockIdx.x;          // h*16 + m
    const int h = b >> 4, m = b & 15;
    const int d = threadIdx.x;
    float gm = -3.0e38f;
#pragma unroll
    for (int c = 0; c < NCH; ++c)
        gm = fmaxf(gm, pmu[(h*NCH + c)*MM + m]);
    float stot = 0.f, a = 0.f;
#pragma unroll
    for (int c = 0; c < NCH; ++c) {
        const float f = __expf(pmu[(h*NCH + c)*MM + m] - gm);
        stot += ps[(h*NCH + c)*MM + m] * f;
        a += pacc[((size_t)(h*NCH + c)*MM + m)*DD + d] * f;
    }
    out[m*NN + h*DD + d] = a / stot;
}

extern "C" void kernel_launch(void* const* d_in, const int* in_sizes, int n_in,
                              void* d_out, int out_size, void* d_ws, size_t ws_size,
                              hipStream_t stream) {
    const float* X  = (const float*)d_in[0];
    const float* Wq = (const float*)d_in[1];
    const float* Wk = (const float*)d_in[2];
    const float* Wv = (const float*)d_in[3];
    const float* cK = (const float*)d_in[4];
    const float* cV = (const float*)d_in[5];
    float* out = (float*)d_out;

    float* ws     = (float*)d_ws;
    float* qkv    = ws;
    float* pmu_p  = ws + 3*HN*MM*DD;
    float* ps_p   = pmu_p + HN*NCH*MM;
    float* pacc_p = ps_p + HN*NCH*MM;

    hipMemsetAsync(qkv, 0, (size_t)3*HN*MM*DD*sizeof(float), stream);
    qkv_kernel<<<768, 256, 0, stream>>>(X, Wq, Wk, Wv, qkv);
    attn_partial3<<<dim3(NCH, HN), 256, 0, stream>>>(cK, cV, qkv, pmu_p, ps_p, pacc_p);
    combine_kernel<<<HN*MM, 128, 0, stream>>>(pmu_p, ps_p, pacc_p, out);
}